// Round 10
// baseline (1293.449 us; speedup 1.0000x reference)
//
#include <hip/hip_runtime.h>
#include <cstdint>
#include <cstddef>

#define B_ 4
#define T_ 12
#define N_ 10000
#define FIN_ 16
#define H_ 64
#define E_ 160000
#define BT_ (B_*T_)          // 48
#define ROWS_ (BT_*N_)       // 480000
#define GRU_ROWS_ (B_*N_)    // 40000
#define PAD_ 68              // padded LDS row (floats) for k_agg

__device__ __forceinline__ float sigmoidf_(float x){ return 1.0f/(1.0f + __expf(-x)); }
__device__ __forceinline__ float tanhf_(float x){
  float ax = fabsf(x);
  float e  = __expf(-2.0f*ax);
  float t  = (1.0f - e)/(1.0f + e);
  return copysignf(t, x);
}

// ---------------------------------------------------------------------------
// A[n][bt][h] = relu(x[bt][n] @ W_pre + b_pre)   (transposed output layout)
// ---------------------------------------------------------------------------
__global__ __launch_bounds__(256) void k_pre(const float* __restrict__ x,
    const float* __restrict__ Wp, const float* __restrict__ bp,
    float* __restrict__ A){
  __shared__ float sW[FIN_*H_];
  __shared__ float sb[H_];
  for (int i = threadIdx.x; i < FIN_*H_; i += 256) sW[i] = Wp[i];
  if (threadIdx.x < H_) sb[threadIdx.x] = bp[threadIdx.x];
  __syncthreads();
  int r = blockIdx.x*256 + threadIdx.x;
  if (r >= ROWS_) return;
  int bt = r / N_;
  int n  = r - bt*N_;
  const float4* xr = reinterpret_cast<const float4*>(x + (size_t)r*FIN_);
  float4 xv[4];
  #pragma unroll
  for (int i=0;i<4;i++) xv[i] = xr[i];
  const float* xk = reinterpret_cast<const float*>(xv);
  float4 acc[16];
  #pragma unroll
  for (int j=0;j<16;j++) acc[j] = reinterpret_cast<const float4*>(sb)[j];
  #pragma unroll
  for (int k=0;k<16;k++){
    float a = xk[k];
    const float4* wr = reinterpret_cast<const float4*>(sW + k*H_);
    #pragma unroll
    for (int j=0;j<16;j++){
      float4 w = wr[j];
      acc[j].x = fmaf(a, w.x, acc[j].x);
      acc[j].y = fmaf(a, w.y, acc[j].y);
      acc[j].z = fmaf(a, w.z, acc[j].z);
      acc[j].w = fmaf(a, w.w, acc[j].w);
    }
  }
  float4* outp = reinterpret_cast<float4*>(A + ((size_t)n*BT_ + bt)*H_);
  #pragma unroll
  for (int j=0;j<16;j++){
    float4 o = acc[j];
    o.x = fmaxf(o.x, 0.f); o.y = fmaxf(o.y, 0.f);
    o.z = fmaxf(o.z, 0.f); o.w = fmaxf(o.w, 0.f);
    outp[j] = o;
  }
}

// ---------------------------------------------------------------------------
__global__ void k_deg(const int* __restrict__ ei, const float* __restrict__ ew,
                      float* __restrict__ wdeg, int* __restrict__ cnt){
  int e = blockIdx.x*256 + threadIdx.x;
  if (e >= E_) return;
  int d = ei[E_ + e];
  atomicAdd(&wdeg[d], ew[e]);
  atomicAdd(&cnt[d], 1);
}

__global__ __launch_bounds__(1024) void k_scan(const int* __restrict__ cnt,
                                               int* __restrict__ rs){
  __shared__ int sb[1024];
  int tid = threadIdx.x;
  int base = tid*10;
  int loc[10]; int s = 0;
  #pragma unroll
  for (int j=0;j<10;j++){
    loc[j] = s;
    int v = (base+j < N_) ? cnt[base+j] : 0;
    s += v;
  }
  sb[tid] = s;
  __syncthreads();
  for (int off=1; off<1024; off<<=1){
    int v = (tid >= off) ? sb[tid-off] : 0;
    __syncthreads();
    sb[tid] += v;
    __syncthreads();
  }
  int pre = (tid>0) ? sb[tid-1] : 0;
  #pragma unroll
  for (int j=0;j<10;j++){
    if (base+j <= N_) rs[base+j] = pre + loc[j];
  }
}

__global__ void k_dinv(const float* __restrict__ wdeg, float* __restrict__ dinv){
  int i = blockIdx.x*256 + threadIdx.x;
  if (i >= N_) return;
  float dg = wdeg[i];
  dinv[i] = (dg > 0.f) ? rsqrtf(dg) : 0.f;
}

__global__ void k_fill(const int* __restrict__ ei, const float* __restrict__ ew,
                       const float* __restrict__ dinv, const int* __restrict__ rs,
                       int* __restrict__ fillc, int* __restrict__ src_s,
                       float* __restrict__ w_s){
  int e = blockIdx.x*256 + threadIdx.x;
  if (e >= E_) return;
  int s = ei[e], d = ei[E_ + e];
  float wn = dinv[s]*ew[e]*dinv[d];
  int slot = rs[d] + atomicAdd(&fillc[d], 1);
  src_s[slot] = s;
  w_s[slot]  = wn;
}

// ---------------------------------------------------------------------------
// Fused layer in [n][bt][h] layout. Block = one node n (256 thr, 4 waves).
//   G = sum_e w_e * Ain[src_e] ; Aout[n] = relu( G@Wl + Ain[n]@Wr + b )
// ---------------------------------------------------------------------------
__global__ __launch_bounds__(256) void k_agg(const float* __restrict__ Ain,
    float* __restrict__ Aout, const float* __restrict__ Wl,
    const float* __restrict__ Wr, const float* __restrict__ bc,
    const int* __restrict__ rs, const int* __restrict__ src_s,
    const float* __restrict__ w_s){
  __shared__ float As[BT_*PAD_];
  __shared__ float Gs[BT_*PAD_];
  int n = blockIdx.x;
  int tid = threadIdx.x;
  const float4* Ain4 = reinterpret_cast<const float4*>(Ain + (size_t)n*BT_*H_);
  #pragma unroll
  for (int j=0;j<3;j++){
    int i = tid + j*256;
    int bt = i >> 4, c4 = i & 15;
    *reinterpret_cast<float4*>(As + bt*PAD_ + c4*4) = Ain4[i];
  }
  int wv = tid >> 6, L = tid & 63;
  int start = rs[n], end = rs[n+1];
  float4 acc[3];
  #pragma unroll
  for (int j=0;j<3;j++) acc[j] = make_float4(0.f,0.f,0.f,0.f);
  int e = start;
  for (; e+3 < end; e += 4){
    int   s0=src_s[e], s1=src_s[e+1], s2=src_s[e+2], s3=src_s[e+3];
    float w0=w_s[e],  w1=w_s[e+1],  w2=w_s[e+2],  w3=w_s[e+3];
    const float4* p0 = reinterpret_cast<const float4*>(Ain) + (size_t)s0*768 + wv*192 + L;
    const float4* p1 = reinterpret_cast<const float4*>(Ain) + (size_t)s1*768 + wv*192 + L;
    const float4* p2 = reinterpret_cast<const float4*>(Ain) + (size_t)s2*768 + wv*192 + L;
    const float4* p3 = reinterpret_cast<const float4*>(Ain) + (size_t)s3*768 + wv*192 + L;
    float4 v0[3], v1[3], v2[3], v3[3];
    #pragma unroll
    for (int j=0;j<3;j++){ v0[j]=p0[j*64]; v1[j]=p1[j*64]; v2[j]=p2[j*64]; v3[j]=p3[j*64]; }
    #pragma unroll
    for (int j=0;j<3;j++){
      acc[j].x = fmaf(w0, v0[j].x, acc[j].x); acc[j].y = fmaf(w0, v0[j].y, acc[j].y);
      acc[j].z = fmaf(w0, v0[j].z, acc[j].z); acc[j].w = fmaf(w0, v0[j].w, acc[j].w);
      acc[j].x = fmaf(w1, v1[j].x, acc[j].x); acc[j].y = fmaf(w1, v1[j].y, acc[j].y);
      acc[j].z = fmaf(w1, v1[j].z, acc[j].z); acc[j].w = fmaf(w1, v1[j].w, acc[j].w);
      acc[j].x = fmaf(w2, v2[j].x, acc[j].x); acc[j].y = fmaf(w2, v2[j].y, acc[j].y);
      acc[j].z = fmaf(w2, v2[j].z, acc[j].z); acc[j].w = fmaf(w2, v2[j].w, acc[j].w);
      acc[j].x = fmaf(w3, v3[j].x, acc[j].x); acc[j].y = fmaf(w3, v3[j].y, acc[j].y);
      acc[j].z = fmaf(w3, v3[j].z, acc[j].z); acc[j].w = fmaf(w3, v3[j].w, acc[j].w);
    }
  }
  for (; e < end; ++e){
    int s0 = src_s[e]; float w0 = w_s[e];
    const float4* p0 = reinterpret_cast<const float4*>(Ain) + (size_t)s0*768 + wv*192 + L;
    #pragma unroll
    for (int j=0;j<3;j++){
      float4 v = p0[j*64];
      acc[j].x = fmaf(w0, v.x, acc[j].x); acc[j].y = fmaf(w0, v.y, acc[j].y);
      acc[j].z = fmaf(w0, v.z, acc[j].z); acc[j].w = fmaf(w0, v.w, acc[j].w);
    }
  }
  {
    int bt0 = wv*12 + (L>>4), c4 = (L&15)*4;
    #pragma unroll
    for (int j=0;j<3;j++)
      *reinterpret_cast<float4*>(Gs + (bt0 + j*4)*PAD_ + c4) = acc[j];
  }
  __syncthreads();
  int bt0 = wv*12 + (L>>4);
  int c4  = (L&15)*4;
  float4 bv = *reinterpret_cast<const float4*>(bc + c4);
  float4 out[3];
  #pragma unroll
  for (int j=0;j<3;j++) out[j] = bv;
  #pragma unroll 2
  for (int k4=0;k4<16;k4++){
    float4 wl[4], wr[4];
    #pragma unroll
    for (int i=0;i<4;i++){
      wl[i] = *reinterpret_cast<const float4*>(Wl + (k4*4+i)*H_ + c4);
      wr[i] = *reinterpret_cast<const float4*>(Wr + (k4*4+i)*H_ + c4);
    }
    #pragma unroll
    for (int j=0;j<3;j++){
      float4 g4 = *reinterpret_cast<const float4*>(Gs + (bt0 + j*4)*PAD_ + k4*4);
      float4 a4 = *reinterpret_cast<const float4*>(As + (bt0 + j*4)*PAD_ + k4*4);
      out[j].x = fmaf(g4.x, wl[0].x, out[j].x); out[j].y = fmaf(g4.x, wl[0].y, out[j].y);
      out[j].z = fmaf(g4.x, wl[0].z, out[j].z); out[j].w = fmaf(g4.x, wl[0].w, out[j].w);
      out[j].x = fmaf(g4.y, wl[1].x, out[j].x); out[j].y = fmaf(g4.y, wl[1].y, out[j].y);
      out[j].z = fmaf(g4.y, wl[1].z, out[j].z); out[j].w = fmaf(g4.y, wl[1].w, out[j].w);
      out[j].x = fmaf(g4.z, wl[2].x, out[j].x); out[j].y = fmaf(g4.z, wl[2].y, out[j].y);
      out[j].z = fmaf(g4.z, wl[2].z, out[j].z); out[j].w = fmaf(g4.z, wl[2].w, out[j].w);
      out[j].x = fmaf(g4.w, wl[3].x, out[j].x); out[j].y = fmaf(g4.w, wl[3].y, out[j].y);
      out[j].z = fmaf(g4.w, wl[3].z, out[j].z); out[j].w = fmaf(g4.w, wl[3].w, out[j].w);
      out[j].x = fmaf(a4.x, wr[0].x, out[j].x); out[j].y = fmaf(a4.x, wr[0].y, out[j].y);
      out[j].z = fmaf(a4.x, wr[0].z, out[j].z); out[j].w = fmaf(a4.x, wr[0].w, out[j].w);
      out[j].x = fmaf(a4.y, wr[1].x, out[j].x); out[j].y = fmaf(a4.y, wr[1].y, out[j].y);
      out[j].z = fmaf(a4.y, wr[1].z, out[j].z); out[j].w = fmaf(a4.y, wr[1].w, out[j].w);
      out[j].x = fmaf(a4.z, wr[2].x, out[j].x); out[j].y = fmaf(a4.z, wr[2].y, out[j].y);
      out[j].z = fmaf(a4.z, wr[2].z, out[j].z); out[j].w = fmaf(a4.z, wr[2].w, out[j].w);
      out[j].x = fmaf(a4.w, wr[3].x, out[j].x); out[j].y = fmaf(a4.w, wr[3].y, out[j].y);
      out[j].z = fmaf(a4.w, wr[3].z, out[j].z); out[j].w = fmaf(a4.w, wr[3].w, out[j].w);
    }
  }
  float4* Aout4 = reinterpret_cast<float4*>(Aout + (size_t)n*BT_*H_);
  #pragma unroll
  for (int j=0;j<3;j++){
    float4 o = out[j];
    o.x = fmaxf(o.x, 0.f); o.y = fmaxf(o.y, 0.f);
    o.z = fmaxf(o.z, 0.f); o.w = fmaxf(o.w, 0.f);
    Aout4[wv*192 + j*64 + L] = o;
  }
}

// ---------------------------------------------------------------------------
// GRU over T=12, [n][bt][h] layout. Block 1024 thr = 16 waves; wave = 5 rows;
// lane = channel. 80 rows/block -> grid 500 = 2 clean CU rounds (vs 625/3
// rounds = 18% tail idle at R7). W k-major in LDS (96KB, base+imm b128
// reads); x/h per-wave LDS slices (40KB). k4 unroll 4, t unroll 1 (R6 spill
// lesson: watch FETCH_SIZE ~61MB; if it explodes, revert to 4 rows/wave).
// ---------------------------------------------------------------------------
__global__ __launch_bounds__(1024) void k_gru(const float* __restrict__ A,
    const float* __restrict__ Wih, const float* __restrict__ Whh,
    const float* __restrict__ bih, const float* __restrict__ bhh,
    float* __restrict__ out){
  extern __shared__ float lds[];
  float* Wk = lds;                      // [6][16][64][4] floats = 24576 (96KB)
  int tid = threadIdx.x;
  int wv = tid >> 6;
  int lane = tid & 63;
  float* xs = lds + 24576 + wv*640;     // [5][64]
  float* hs = xs + 320;                 // [5][64]
  // stage W k-major: dst = s*4096 + c4*256 + o*4
  #pragma unroll
  for (int j=0;j<6;j++){
    int i = tid + j*1024;               // float4 idx 0..6143
    int g = i >> 4, c4 = i & 15;
    int s = g >> 6, o = g & 63;
    float4 v = (g < 192)
      ? *reinterpret_cast<const float4*>(Wih + g*H_ + c4*4)
      : *reinterpret_cast<const float4*>(Whh + (g-192)*H_ + c4*4);
    *reinterpret_cast<float4*>(Wk + s*4096 + c4*256 + o*4) = v;
  }
  __syncthreads();
  float hreg[5];
  #pragma unroll
  for (int r=0;r<5;r++){ hreg[r] = 0.f; hs[r*64 + lane] = 0.f; }

  const float* wbi = Wk + lane*4;          // ih gates: + s*4096 + k4*256
  const float* wbh = Wk + 12288 + lane*4;  // hh gates

  int row0 = blockIdx.x*80 + wv*5;      // N_%5==0 -> wave rows share b
  int bb = row0 / N_;
  int nn0 = row0 - bb*N_;
  float bi[3], bh[3];
  #pragma unroll
  for (int s=0;s<3;s++){ bi[s] = bih[s*64 + lane]; bh[s] = bhh[s*64 + lane]; }
  int xr = lane >> 4, xc4 = lane & 15;  // rows 0..3 staging slot
  const float* Abase  = A + ((size_t)(nn0 + xr)*BT_ + bb*T_)*H_;
  const float* Abase4 = A + ((size_t)(nn0 + 4)*BT_ + bb*T_)*H_;  // row 4 (lane<16)

  float4 xv  = *reinterpret_cast<const float4*>(Abase + xc4*4);
  float4 xv4 = make_float4(0.f,0.f,0.f,0.f);
  if (lane < 16) xv4 = *reinterpret_cast<const float4*>(Abase4 + lane*4);
  #pragma unroll 1
  for (int t=0; t<T_; t++){
    *reinterpret_cast<float4*>(xs + xr*64 + xc4*4) = xv;
    if (lane < 16) *reinterpret_cast<float4*>(xs + 4*64 + lane*4) = xv4;
    int tn = (t < T_-1) ? t+1 : t;
    float4 xvn  = *reinterpret_cast<const float4*>(Abase + (size_t)tn*H_ + xc4*4);
    float4 xv4n = xv4;
    if (lane < 16) xv4n = *reinterpret_cast<const float4*>(Abase4 + (size_t)tn*H_ + lane*4);

    float ai[3][5], ah[3][5];
    #pragma unroll
    for (int s=0;s<3;s++)
      #pragma unroll
      for (int r=0;r<5;r++){ ai[s][r] = bi[s]; ah[s][r] = bh[s]; }

    #pragma unroll 4
    for (int k4=0;k4<16;k4++){
      float4 wi[3], wh[3];
      #pragma unroll
      for (int s=0;s<3;s++){
        wi[s] = *reinterpret_cast<const float4*>(wbi + s*4096 + k4*256);
        wh[s] = *reinterpret_cast<const float4*>(wbh + s*4096 + k4*256);
      }
      #pragma unroll
      for (int r=0;r<5;r++){
        float4 xw = *reinterpret_cast<const float4*>(xs + r*64 + k4*4);
        float4 hw = *reinterpret_cast<const float4*>(hs + r*64 + k4*4);
        #pragma unroll
        for (int s=0;s<3;s++){
          ai[s][r] = fmaf(wi[s].x, xw.x, ai[s][r]);
          ai[s][r] = fmaf(wi[s].y, xw.y, ai[s][r]);
          ai[s][r] = fmaf(wi[s].z, xw.z, ai[s][r]);
          ai[s][r] = fmaf(wi[s].w, xw.w, ai[s][r]);
          ah[s][r] = fmaf(wh[s].x, hw.x, ah[s][r]);
          ah[s][r] = fmaf(wh[s].y, hw.y, ah[s][r]);
          ah[s][r] = fmaf(wh[s].z, hw.z, ah[s][r]);
          ah[s][r] = fmaf(wh[s].w, hw.w, ah[s][r]);
        }
      }
    }
    #pragma unroll
    for (int r=0;r<5;r++){
      float rr = sigmoidf_(ai[0][r] + ah[0][r]);
      float zz = sigmoidf_(ai[1][r] + ah[1][r]);
      float ng = tanhf_(ai[2][r] + rr*ah[2][r]);
      float hn = (1.f - zz)*ng + zz*hreg[r];
      hreg[r] = hn;
      hs[r*64 + lane] = hn;
    }
    xv = xvn; xv4 = xv4n;
  }
  #pragma unroll
  for (int r=0;r<5;r++)
    out[(size_t)(row0 + r)*H_ + lane] = hreg[r];
}

// ---------------------------------------------------------------------------
extern "C" void kernel_launch(void* const* d_in, const int* in_sizes, int n_in,
                              void* d_out, int out_size, void* d_ws, size_t ws_size,
                              hipStream_t stream){
  const float* x     = (const float*)d_in[0];
  const int*   ei    = (const int*)d_in[1];
  const float* ew    = (const float*)d_in[2];
  const float* Wpre  = (const float*)d_in[3];
  const float* bpre  = (const float*)d_in[4];
  const float* Wlin  = (const float*)d_in[5];
  const float* Wroot = (const float*)d_in[6];
  const float* bconv = (const float*)d_in[7];
  const float* Wih   = (const float*)d_in[8];
  const float* Whh   = (const float*)d_in[9];
  const float* bih   = (const float*)d_in[10];
  const float* bhh   = (const float*)d_in[11];
  float* out = (float*)d_out;

  float* ws   = (float*)d_ws;
  float* A0   = ws;                       // 30,720,000 f  [n][bt][h]
  float* A1   = A0 + (size_t)ROWS_*H_;    // 30,720,000 f
  float* wdeg = A1 + (size_t)ROWS_*H_;    // N
  float* dinv = wdeg + N_;                // N
  float* w_s  = dinv + N_;                // E
  int*   cnt   = (int*)(w_s + E_);        // N
  int*   fillc = cnt + N_;                // N
  int*   rs    = fillc + N_;              // N+1
  int*   src_s = rs + (N_+1);             // E
  // total ~247 MB (known-safe)

  hipMemsetAsync(wdeg, 0, N_*sizeof(float), stream);
  hipMemsetAsync(cnt,  0, 2*N_*sizeof(int), stream);   // cnt + fillc contiguous

  k_pre<<<ROWS_/256, 256, 0, stream>>>(x, Wpre, bpre, A0);
  k_deg<<<E_/256, 256, 0, stream>>>(ei, ew, wdeg, cnt);
  k_scan<<<1, 1024, 0, stream>>>(cnt, rs);
  k_dinv<<<(N_+255)/256, 256, 0, stream>>>(wdeg, dinv);
  k_fill<<<E_/256, 256, 0, stream>>>(ei, ew, dinv, rs, fillc, src_s, w_s);

  k_agg<<<N_, 256, 0, stream>>>(A0, A1, Wlin,         Wroot,         bconv,
                                rs, src_s, w_s);
  k_agg<<<N_, 256, 0, stream>>>(A1, A0, Wlin + H_*H_, Wroot + H_*H_, bconv + H_,
                                rs, src_s, w_s);

  hipFuncSetAttribute((const void*)k_gru,
      hipFuncAttributeMaxDynamicSharedMemorySize, 139264);
  k_gru<<<GRU_ROWS_/80, 1024, 139264, stream>>>(A0, Wih, Whh, bih, bhh, out);
}

// Round 11
// 1138.301 us; speedup vs baseline: 1.1363x; 1.1363x over previous
//
#include <hip/hip_runtime.h>
#include <cstdint>
#include <cstddef>

#define B_ 4
#define T_ 12
#define N_ 10000
#define FIN_ 16
#define H_ 64
#define E_ 160000
#define BT_ (B_*T_)          // 48
#define ROWS_ (BT_*N_)       // 480000
#define GRU_ROWS_ (B_*N_)    // 40000
#define PAD_ 68              // padded LDS row (floats) for k_agg

__device__ __forceinline__ float sigmoidf_(float x){ return 1.0f/(1.0f + __expf(-x)); }
__device__ __forceinline__ float tanhf_(float x){
  float ax = fabsf(x);
  float e  = __expf(-2.0f*ax);
  float t  = (1.0f - e)/(1.0f + e);
  return copysignf(t, x);
}

// ---------------------------------------------------------------------------
// A[n][bt][h] = relu(x[bt][n] @ W_pre + b_pre)   (transposed output layout)
// ---------------------------------------------------------------------------
__global__ __launch_bounds__(256) void k_pre(const float* __restrict__ x,
    const float* __restrict__ Wp, const float* __restrict__ bp,
    float* __restrict__ A){
  __shared__ float sW[FIN_*H_];
  __shared__ float sb[H_];
  for (int i = threadIdx.x; i < FIN_*H_; i += 256) sW[i] = Wp[i];
  if (threadIdx.x < H_) sb[threadIdx.x] = bp[threadIdx.x];
  __syncthreads();
  int r = blockIdx.x*256 + threadIdx.x;
  if (r >= ROWS_) return;
  int bt = r / N_;
  int n  = r - bt*N_;
  const float4* xr = reinterpret_cast<const float4*>(x + (size_t)r*FIN_);
  float4 xv[4];
  #pragma unroll
  for (int i=0;i<4;i++) xv[i] = xr[i];
  const float* xk = reinterpret_cast<const float*>(xv);
  float4 acc[16];
  #pragma unroll
  for (int j=0;j<16;j++) acc[j] = reinterpret_cast<const float4*>(sb)[j];
  #pragma unroll
  for (int k=0;k<16;k++){
    float a = xk[k];
    const float4* wr = reinterpret_cast<const float4*>(sW + k*H_);
    #pragma unroll
    for (int j=0;j<16;j++){
      float4 w = wr[j];
      acc[j].x = fmaf(a, w.x, acc[j].x);
      acc[j].y = fmaf(a, w.y, acc[j].y);
      acc[j].z = fmaf(a, w.z, acc[j].z);
      acc[j].w = fmaf(a, w.w, acc[j].w);
    }
  }
  float4* outp = reinterpret_cast<float4*>(A + ((size_t)n*BT_ + bt)*H_);
  #pragma unroll
  for (int j=0;j<16;j++){
    float4 o = acc[j];
    o.x = fmaxf(o.x, 0.f); o.y = fmaxf(o.y, 0.f);
    o.z = fmaxf(o.z, 0.f); o.w = fmaxf(o.w, 0.f);
    outp[j] = o;
  }
}

// ---------------------------------------------------------------------------
__global__ void k_deg(const int* __restrict__ ei, const float* __restrict__ ew,
                      float* __restrict__ wdeg, int* __restrict__ cnt){
  int e = blockIdx.x*256 + threadIdx.x;
  if (e >= E_) return;
  int d = ei[E_ + e];
  atomicAdd(&wdeg[d], ew[e]);
  atomicAdd(&cnt[d], 1);
}

__global__ __launch_bounds__(1024) void k_scan(const int* __restrict__ cnt,
                                               int* __restrict__ rs){
  __shared__ int sb[1024];
  int tid = threadIdx.x;
  int base = tid*10;
  int loc[10]; int s = 0;
  #pragma unroll
  for (int j=0;j<10;j++){
    loc[j] = s;
    int v = (base+j < N_) ? cnt[base+j] : 0;
    s += v;
  }
  sb[tid] = s;
  __syncthreads();
  for (int off=1; off<1024; off<<=1){
    int v = (tid >= off) ? sb[tid-off] : 0;
    __syncthreads();
    sb[tid] += v;
    __syncthreads();
  }
  int pre = (tid>0) ? sb[tid-1] : 0;
  #pragma unroll
  for (int j=0;j<10;j++){
    if (base+j <= N_) rs[base+j] = pre + loc[j];
  }
}

__global__ void k_dinv(const float* __restrict__ wdeg, float* __restrict__ dinv){
  int i = blockIdx.x*256 + threadIdx.x;
  if (i >= N_) return;
  float dg = wdeg[i];
  dinv[i] = (dg > 0.f) ? rsqrtf(dg) : 0.f;
}

__global__ void k_fill(const int* __restrict__ ei, const float* __restrict__ ew,
                       const float* __restrict__ dinv, const int* __restrict__ rs,
                       int* __restrict__ fillc, int* __restrict__ src_s,
                       float* __restrict__ w_s){
  int e = blockIdx.x*256 + threadIdx.x;
  if (e >= E_) return;
  int s = ei[e], d = ei[E_ + e];
  float wn = dinv[s]*ew[e]*dinv[d];
  int slot = rs[d] + atomicAdd(&fillc[d], 1);
  src_s[slot] = s;
  w_s[slot]  = wn;
}

// ---------------------------------------------------------------------------
// Fused layer in [n][bt][h] layout. Block = one node n (256 thr, 4 waves).
//   G = sum_e w_e * Ain[src_e] ; Aout[n] = relu( G@Wl + Ain[n]@Wr + b )
// ---------------------------------------------------------------------------
__global__ __launch_bounds__(256) void k_agg(const float* __restrict__ Ain,
    float* __restrict__ Aout, const float* __restrict__ Wl,
    const float* __restrict__ Wr, const float* __restrict__ bc,
    const int* __restrict__ rs, const int* __restrict__ src_s,
    const float* __restrict__ w_s){
  __shared__ float As[BT_*PAD_];
  __shared__ float Gs[BT_*PAD_];
  int n = blockIdx.x;
  int tid = threadIdx.x;
  const float4* Ain4 = reinterpret_cast<const float4*>(Ain + (size_t)n*BT_*H_);
  #pragma unroll
  for (int j=0;j<3;j++){
    int i = tid + j*256;
    int bt = i >> 4, c4 = i & 15;
    *reinterpret_cast<float4*>(As + bt*PAD_ + c4*4) = Ain4[i];
  }
  int wv = tid >> 6, L = tid & 63;
  int start = rs[n], end = rs[n+1];
  float4 acc[3];
  #pragma unroll
  for (int j=0;j<3;j++) acc[j] = make_float4(0.f,0.f,0.f,0.f);
  int e = start;
  for (; e+3 < end; e += 4){
    int   s0=src_s[e], s1=src_s[e+1], s2=src_s[e+2], s3=src_s[e+3];
    float w0=w_s[e],  w1=w_s[e+1],  w2=w_s[e+2],  w3=w_s[e+3];
    const float4* p0 = reinterpret_cast<const float4*>(Ain) + (size_t)s0*768 + wv*192 + L;
    const float4* p1 = reinterpret_cast<const float4*>(Ain) + (size_t)s1*768 + wv*192 + L;
    const float4* p2 = reinterpret_cast<const float4*>(Ain) + (size_t)s2*768 + wv*192 + L;
    const float4* p3 = reinterpret_cast<const float4*>(Ain) + (size_t)s3*768 + wv*192 + L;
    float4 v0[3], v1[3], v2[3], v3[3];
    #pragma unroll
    for (int j=0;j<3;j++){ v0[j]=p0[j*64]; v1[j]=p1[j*64]; v2[j]=p2[j*64]; v3[j]=p3[j*64]; }
    #pragma unroll
    for (int j=0;j<3;j++){
      acc[j].x = fmaf(w0, v0[j].x, acc[j].x); acc[j].y = fmaf(w0, v0[j].y, acc[j].y);
      acc[j].z = fmaf(w0, v0[j].z, acc[j].z); acc[j].w = fmaf(w0, v0[j].w, acc[j].w);
      acc[j].x = fmaf(w1, v1[j].x, acc[j].x); acc[j].y = fmaf(w1, v1[j].y, acc[j].y);
      acc[j].z = fmaf(w1, v1[j].z, acc[j].z); acc[j].w = fmaf(w1, v1[j].w, acc[j].w);
      acc[j].x = fmaf(w2, v2[j].x, acc[j].x); acc[j].y = fmaf(w2, v2[j].y, acc[j].y);
      acc[j].z = fmaf(w2, v2[j].z, acc[j].z); acc[j].w = fmaf(w2, v2[j].w, acc[j].w);
      acc[j].x = fmaf(w3, v3[j].x, acc[j].x); acc[j].y = fmaf(w3, v3[j].y, acc[j].y);
      acc[j].z = fmaf(w3, v3[j].z, acc[j].z); acc[j].w = fmaf(w3, v3[j].w, acc[j].w);
    }
  }
  for (; e < end; ++e){
    int s0 = src_s[e]; float w0 = w_s[e];
    const float4* p0 = reinterpret_cast<const float4*>(Ain) + (size_t)s0*768 + wv*192 + L;
    #pragma unroll
    for (int j=0;j<3;j++){
      float4 v = p0[j*64];
      acc[j].x = fmaf(w0, v.x, acc[j].x); acc[j].y = fmaf(w0, v.y, acc[j].y);
      acc[j].z = fmaf(w0, v.z, acc[j].z); acc[j].w = fmaf(w0, v.w, acc[j].w);
    }
  }
  {
    int bt0 = wv*12 + (L>>4), c4 = (L&15)*4;
    #pragma unroll
    for (int j=0;j<3;j++)
      *reinterpret_cast<float4*>(Gs + (bt0 + j*4)*PAD_ + c4) = acc[j];
  }
  __syncthreads();
  int bt0 = wv*12 + (L>>4);
  int c4  = (L&15)*4;
  float4 bv = *reinterpret_cast<const float4*>(bc + c4);
  float4 out[3];
  #pragma unroll
  for (int j=0;j<3;j++) out[j] = bv;
  #pragma unroll 2
  for (int k4=0;k4<16;k4++){
    float4 wl[4], wr[4];
    #pragma unroll
    for (int i=0;i<4;i++){
      wl[i] = *reinterpret_cast<const float4*>(Wl + (k4*4+i)*H_ + c4);
      wr[i] = *reinterpret_cast<const float4*>(Wr + (k4*4+i)*H_ + c4);
    }
    #pragma unroll
    for (int j=0;j<3;j++){
      float4 g4 = *reinterpret_cast<const float4*>(Gs + (bt0 + j*4)*PAD_ + k4*4);
      float4 a4 = *reinterpret_cast<const float4*>(As + (bt0 + j*4)*PAD_ + k4*4);
      out[j].x = fmaf(g4.x, wl[0].x, out[j].x); out[j].y = fmaf(g4.x, wl[0].y, out[j].y);
      out[j].z = fmaf(g4.x, wl[0].z, out[j].z); out[j].w = fmaf(g4.x, wl[0].w, out[j].w);
      out[j].x = fmaf(g4.y, wl[1].x, out[j].x); out[j].y = fmaf(g4.y, wl[1].y, out[j].y);
      out[j].z = fmaf(g4.y, wl[1].z, out[j].z); out[j].w = fmaf(g4.y, wl[1].w, out[j].w);
      out[j].x = fmaf(g4.z, wl[2].x, out[j].x); out[j].y = fmaf(g4.z, wl[2].y, out[j].y);
      out[j].z = fmaf(g4.z, wl[2].z, out[j].z); out[j].w = fmaf(g4.z, wl[2].w, out[j].w);
      out[j].x = fmaf(g4.w, wl[3].x, out[j].x); out[j].y = fmaf(g4.w, wl[3].y, out[j].y);
      out[j].z = fmaf(g4.w, wl[3].z, out[j].z); out[j].w = fmaf(g4.w, wl[3].w, out[j].w);
      out[j].x = fmaf(a4.x, wr[0].x, out[j].x); out[j].y = fmaf(a4.x, wr[0].y, out[j].y);
      out[j].z = fmaf(a4.x, wr[0].z, out[j].z); out[j].w = fmaf(a4.x, wr[0].w, out[j].w);
      out[j].x = fmaf(a4.y, wr[1].x, out[j].x); out[j].y = fmaf(a4.y, wr[1].y, out[j].y);
      out[j].z = fmaf(a4.y, wr[1].z, out[j].z); out[j].w = fmaf(a4.y, wr[1].w, out[j].w);
      out[j].x = fmaf(a4.z, wr[2].x, out[j].x); out[j].y = fmaf(a4.z, wr[2].y, out[j].y);
      out[j].z = fmaf(a4.z, wr[2].z, out[j].z); out[j].w = fmaf(a4.z, wr[2].w, out[j].w);
      out[j].x = fmaf(a4.w, wr[3].x, out[j].x); out[j].y = fmaf(a4.w, wr[3].y, out[j].y);
      out[j].z = fmaf(a4.w, wr[3].z, out[j].z); out[j].w = fmaf(a4.w, wr[3].w, out[j].w);
    }
  }
  float4* Aout4 = reinterpret_cast<float4*>(Aout + (size_t)n*BT_*H_);
  #pragma unroll
  for (int j=0;j<3;j++){
    float4 o = out[j];
    o.x = fmaxf(o.x, 0.f); o.y = fmaxf(o.y, 0.f);
    o.z = fmaxf(o.z, 0.f); o.w = fmaxf(o.w, 0.f);
    Aout4[wv*192 + j*64 + L] = o;
  }
}

// ---------------------------------------------------------------------------
// GRU over T=12, [n][bt][h] layout. R7 structure (best measured: 524us):
// 1024 thr = 16 waves; wave = 4 rows; lane = channel; W k-major LDS 96KB.
// CHANGE vs R7: x reads moved OFF the LDS pipe. x addresses are wave-uniform
// (readfirstlane-forced), so per-k4 x chunks load straight from global
// (SMEM/uniform-VMEM pipe, L1-hot, same total bytes); no x staging in LDS.
// LDS ops/k4/wave: 14 -> 10 (6 W b128 + 4 h b128). h stays in LDS (per-wave
// slice, lockstep, no barriers in t-loop). k4 unroll 4, t unroll 1 (R6 spill
// lesson). Spill canary: FETCH ~61MB, WRITE ~10MB.
// ---------------------------------------------------------------------------
__global__ __launch_bounds__(1024) void k_gru(const float* __restrict__ A,
    const float* __restrict__ Wih, const float* __restrict__ Whh,
    const float* __restrict__ bih, const float* __restrict__ bhh,
    float* __restrict__ out){
  extern __shared__ float lds[];
  float* Wk = lds;                      // [6][16][64][4] floats = 24576 (96KB)
  int tid = threadIdx.x;
  int wv = __builtin_amdgcn_readfirstlane(tid >> 6);  // force SGPR: uniform addrs
  int lane = tid & 63;
  float* hs = lds + 24576 + wv*256;     // [4][64] per-wave h slice
  // stage W k-major: dst = s*4096 + c4*256 + o*4
  #pragma unroll
  for (int j=0;j<6;j++){
    int i = tid + j*1024;               // float4 idx 0..6143
    int g = i >> 4, c4 = i & 15;
    int s = g >> 6, o = g & 63;
    float4 v = (g < 192)
      ? *reinterpret_cast<const float4*>(Wih + g*H_ + c4*4)
      : *reinterpret_cast<const float4*>(Whh + (g-192)*H_ + c4*4);
    *reinterpret_cast<float4*>(Wk + s*4096 + c4*256 + o*4) = v;
  }
  __syncthreads();
  float hreg[4];
  #pragma unroll
  for (int r=0;r<4;r++){ hreg[r] = 0.f; hs[r*64 + lane] = 0.f; }

  const float* wbi = Wk + lane*4;          // ih gates: + s*4096 + k4*256
  const float* wbh = Wk + 12288 + lane*4;  // hh gates

  int row0 = blockIdx.x*64 + wv*4;      // N_%4==0 -> wave rows share b
  int bb = row0 / N_;
  int nn0 = row0 - bb*N_;
  float bi[3], bh[3];
  #pragma unroll
  for (int s=0;s<3;s++){ bi[s] = bih[s*64 + lane]; bh[s] = bhh[s*64 + lane]; }
  // wave-uniform x row bases (t=0); advance by H_ per t
  const float* Ax0 = A + ((size_t)(nn0 + 0)*BT_ + bb*T_)*H_;
  const float* Ax1 = A + ((size_t)(nn0 + 1)*BT_ + bb*T_)*H_;
  const float* Ax2 = A + ((size_t)(nn0 + 2)*BT_ + bb*T_)*H_;
  const float* Ax3 = A + ((size_t)(nn0 + 3)*BT_ + bb*T_)*H_;

  #pragma unroll 1
  for (int t=0; t<T_; t++){
    const float* xrow[4] = { Ax0 + t*H_, Ax1 + t*H_, Ax2 + t*H_, Ax3 + t*H_ };

    float ai[3][4], ah[3][4];
    #pragma unroll
    for (int s=0;s<3;s++)
      #pragma unroll
      for (int r=0;r<4;r++){ ai[s][r] = bi[s]; ah[s][r] = bh[s]; }

    #pragma unroll 4
    for (int k4=0;k4<16;k4++){
      float4 wi[3], wh[3];
      #pragma unroll
      for (int s=0;s<3;s++){
        wi[s] = *reinterpret_cast<const float4*>(wbi + s*4096 + k4*256);
        wh[s] = *reinterpret_cast<const float4*>(wbh + s*4096 + k4*256);
      }
      #pragma unroll
      for (int r=0;r<4;r++){
        float4 xw = *reinterpret_cast<const float4*>(xrow[r] + k4*4);  // uniform global
        float4 hw = *reinterpret_cast<const float4*>(hs + r*64 + k4*4);
        #pragma unroll
        for (int s=0;s<3;s++){
          ai[s][r] = fmaf(wi[s].x, xw.x, ai[s][r]);
          ai[s][r] = fmaf(wi[s].y, xw.y, ai[s][r]);
          ai[s][r] = fmaf(wi[s].z, xw.z, ai[s][r]);
          ai[s][r] = fmaf(wi[s].w, xw.w, ai[s][r]);
          ah[s][r] = fmaf(wh[s].x, hw.x, ah[s][r]);
          ah[s][r] = fmaf(wh[s].y, hw.y, ah[s][r]);
          ah[s][r] = fmaf(wh[s].z, hw.z, ah[s][r]);
          ah[s][r] = fmaf(wh[s].w, hw.w, ah[s][r]);
        }
      }
    }
    #pragma unroll
    for (int r=0;r<4;r++){
      float rr = sigmoidf_(ai[0][r] + ah[0][r]);
      float zz = sigmoidf_(ai[1][r] + ah[1][r]);
      float ng = tanhf_(ai[2][r] + rr*ah[2][r]);
      float hn = (1.f - zz)*ng + zz*hreg[r];
      hreg[r] = hn;
      hs[r*64 + lane] = hn;
    }
  }
  #pragma unroll
  for (int r=0;r<4;r++)
    out[(size_t)(row0 + r)*H_ + lane] = hreg[r];
}

// ---------------------------------------------------------------------------
extern "C" void kernel_launch(void* const* d_in, const int* in_sizes, int n_in,
                              void* d_out, int out_size, void* d_ws, size_t ws_size,
                              hipStream_t stream){
  const float* x     = (const float*)d_in[0];
  const int*   ei    = (const int*)d_in[1];
  const float* ew    = (const float*)d_in[2];
  const float* Wpre  = (const float*)d_in[3];
  const float* bpre  = (const float*)d_in[4];
  const float* Wlin  = (const float*)d_in[5];
  const float* Wroot = (const float*)d_in[6];
  const float* bconv = (const float*)d_in[7];
  const float* Wih   = (const float*)d_in[8];
  const float* Whh   = (const float*)d_in[9];
  const float* bih   = (const float*)d_in[10];
  const float* bhh   = (const float*)d_in[11];
  float* out = (float*)d_out;

  float* ws   = (float*)d_ws;
  float* A0   = ws;                       // 30,720,000 f  [n][bt][h]
  float* A1   = A0 + (size_t)ROWS_*H_;    // 30,720,000 f
  float* wdeg = A1 + (size_t)ROWS_*H_;    // N
  float* dinv = wdeg + N_;                // N
  float* w_s  = dinv + N_;                // E
  int*   cnt   = (int*)(w_s + E_);        // N
  int*   fillc = cnt + N_;                // N
  int*   rs    = fillc + N_;              // N+1
  int*   src_s = rs + (N_+1);             // E
  // total ~247 MB (known-safe)

  hipMemsetAsync(wdeg, 0, N_*sizeof(float), stream);
  hipMemsetAsync(cnt,  0, 2*N_*sizeof(int), stream);   // cnt + fillc contiguous

  k_pre<<<ROWS_/256, 256, 0, stream>>>(x, Wpre, bpre, A0);
  k_deg<<<E_/256, 256, 0, stream>>>(ei, ew, wdeg, cnt);
  k_scan<<<1, 1024, 0, stream>>>(cnt, rs);
  k_dinv<<<(N_+255)/256, 256, 0, stream>>>(wdeg, dinv);
  k_fill<<<E_/256, 256, 0, stream>>>(ei, ew, dinv, rs, fillc, src_s, w_s);

  k_agg<<<N_, 256, 0, stream>>>(A0, A1, Wlin,         Wroot,         bconv,
                                rs, src_s, w_s);
  k_agg<<<N_, 256, 0, stream>>>(A1, A0, Wlin + H_*H_, Wroot + H_*H_, bconv + H_,
                                rs, src_s, w_s);

  hipFuncSetAttribute((const void*)k_gru,
      hipFuncAttributeMaxDynamicSharedMemorySize, 114688);
  k_gru<<<GRU_ROWS_/64, 1024, 114688, stream>>>(A0, Wih, Whh, bih, bhh, out);
}

// Round 13
// 1072.179 us; speedup vs baseline: 1.2064x; 1.0617x over previous
//
#include <hip/hip_runtime.h>
#include <cstdint>
#include <cstddef>

#define B_ 4
#define T_ 12
#define N_ 10000
#define FIN_ 16
#define H_ 64
#define E_ 160000
#define BT_ (B_*T_)          // 48
#define ROWS_ (BT_*N_)       // 480000
#define GRU_ROWS_ (B_*N_)    // 40000
#define PAD_ 68              // padded LDS row (floats) for k_agg

__device__ __forceinline__ float sigmoidf_(float x){ return 1.0f/(1.0f + __expf(-x)); }
__device__ __forceinline__ float tanhf_(float x){
  float ax = fabsf(x);
  float e  = __expf(-2.0f*ax);
  float t  = (1.0f - e)/(1.0f + e);
  return copysignf(t, x);
}

// ---------------------------------------------------------------------------
// A[n][bt][h] = relu(x[bt][n] @ W_pre + b_pre)   (transposed output layout)
// ---------------------------------------------------------------------------
__global__ __launch_bounds__(256) void k_pre(const float* __restrict__ x,
    const float* __restrict__ Wp, const float* __restrict__ bp,
    float* __restrict__ A){
  __shared__ float sW[FIN_*H_];
  __shared__ float sb[H_];
  for (int i = threadIdx.x; i < FIN_*H_; i += 256) sW[i] = Wp[i];
  if (threadIdx.x < H_) sb[threadIdx.x] = bp[threadIdx.x];
  __syncthreads();
  int r = blockIdx.x*256 + threadIdx.x;
  if (r >= ROWS_) return;
  int bt = r / N_;
  int n  = r - bt*N_;
  const float4* xr = reinterpret_cast<const float4*>(x + (size_t)r*FIN_);
  float4 xv[4];
  #pragma unroll
  for (int i=0;i<4;i++) xv[i] = xr[i];
  const float* xk = reinterpret_cast<const float*>(xv);
  float4 acc[16];
  #pragma unroll
  for (int j=0;j<16;j++) acc[j] = reinterpret_cast<const float4*>(sb)[j];
  #pragma unroll
  for (int k=0;k<16;k++){
    float a = xk[k];
    const float4* wr = reinterpret_cast<const float4*>(sW + k*H_);
    #pragma unroll
    for (int j=0;j<16;j++){
      float4 w = wr[j];
      acc[j].x = fmaf(a, w.x, acc[j].x);
      acc[j].y = fmaf(a, w.y, acc[j].y);
      acc[j].z = fmaf(a, w.z, acc[j].z);
      acc[j].w = fmaf(a, w.w, acc[j].w);
    }
  }
  float4* outp = reinterpret_cast<float4*>(A + ((size_t)n*BT_ + bt)*H_);
  #pragma unroll
  for (int j=0;j<16;j++){
    float4 o = acc[j];
    o.x = fmaxf(o.x, 0.f); o.y = fmaxf(o.y, 0.f);
    o.z = fmaxf(o.z, 0.f); o.w = fmaxf(o.w, 0.f);
    outp[j] = o;
  }
}

// ---------------------------------------------------------------------------
__global__ void k_deg(const int* __restrict__ ei, const float* __restrict__ ew,
                      float* __restrict__ wdeg, int* __restrict__ cnt){
  int e = blockIdx.x*256 + threadIdx.x;
  if (e >= E_) return;
  int d = ei[E_ + e];
  atomicAdd(&wdeg[d], ew[e]);
  atomicAdd(&cnt[d], 1);
}

__global__ __launch_bounds__(1024) void k_scan(const int* __restrict__ cnt,
                                               int* __restrict__ rs){
  __shared__ int sb[1024];
  int tid = threadIdx.x;
  int base = tid*10;
  int loc[10]; int s = 0;
  #pragma unroll
  for (int j=0;j<10;j++){
    loc[j] = s;
    int v = (base+j < N_) ? cnt[base+j] : 0;
    s += v;
  }
  sb[tid] = s;
  __syncthreads();
  for (int off=1; off<1024; off<<=1){
    int v = (tid >= off) ? sb[tid-off] : 0;
    __syncthreads();
    sb[tid] += v;
    __syncthreads();
  }
  int pre = (tid>0) ? sb[tid-1] : 0;
  #pragma unroll
  for (int j=0;j<10;j++){
    if (base+j <= N_) rs[base+j] = pre + loc[j];
  }
}

__global__ void k_dinv(const float* __restrict__ wdeg, float* __restrict__ dinv){
  int i = blockIdx.x*256 + threadIdx.x;
  if (i >= N_) return;
  float dg = wdeg[i];
  dinv[i] = (dg > 0.f) ? rsqrtf(dg) : 0.f;
}

__global__ void k_fill(const int* __restrict__ ei, const float* __restrict__ ew,
                       const float* __restrict__ dinv, const int* __restrict__ rs,
                       int* __restrict__ fillc, int* __restrict__ src_s,
                       float* __restrict__ w_s){
  int e = blockIdx.x*256 + threadIdx.x;
  if (e >= E_) return;
  int s = ei[e], d = ei[E_ + e];
  float wn = dinv[s]*ew[e]*dinv[d];
  int slot = rs[d] + atomicAdd(&fillc[d], 1);
  src_s[slot] = s;
  w_s[slot]  = wn;
}

// ---------------------------------------------------------------------------
// one-time: Whh [192][64] -> k-major Whh_k [3][16][64][4]
// CORRECT (matches R7's verified in-kernel staging):
//   Whh_k[s][k>>2][o][k&3] = Whh[row = s*64 + o][col = k]
// (R12 bug: o and k were swapped -> staged Whh^T -> absmax 7e-3.)
// ---------------------------------------------------------------------------
__global__ void k_wstage(const float* __restrict__ Whh, float* __restrict__ Whh_k){
  int tid = blockIdx.x*256 + threadIdx.x;
  if (tid >= 192*64) return;
  int row = tid >> 6, k = tid & 63;   // row = s*64+o (output), k = input dim
  int s = row >> 6, o = row & 63;
  Whh_k[s*4096 + (k>>2)*256 + o*4 + (k&3)] = Whh[row*64 + k];
}

// ---------------------------------------------------------------------------
// Fused layer in [n][bt][h] layout. Block = one node n (256 thr, 4 waves).
//   G = sum_e w_e * Ain[src_e] ; Aout[n] = relu( G@Wl + Ain[n]@Wr + b )
// ---------------------------------------------------------------------------
__global__ __launch_bounds__(256) void k_agg(const float* __restrict__ Ain,
    float* __restrict__ Aout, const float* __restrict__ Wl,
    const float* __restrict__ Wr, const float* __restrict__ bc,
    const int* __restrict__ rs, const int* __restrict__ src_s,
    const float* __restrict__ w_s){
  __shared__ float As[BT_*PAD_];
  __shared__ float Gs[BT_*PAD_];
  int n = blockIdx.x;
  int tid = threadIdx.x;
  const float4* Ain4 = reinterpret_cast<const float4*>(Ain + (size_t)n*BT_*H_);
  #pragma unroll
  for (int j=0;j<3;j++){
    int i = tid + j*256;
    int bt = i >> 4, c4 = i & 15;
    *reinterpret_cast<float4*>(As + bt*PAD_ + c4*4) = Ain4[i];
  }
  int wv = tid >> 6, L = tid & 63;
  int start = rs[n], end = rs[n+1];
  float4 acc[3];
  #pragma unroll
  for (int j=0;j<3;j++) acc[j] = make_float4(0.f,0.f,0.f,0.f);
  int e = start;
  for (; e+3 < end; e += 4){
    int   s0=src_s[e], s1=src_s[e+1], s2=src_s[e+2], s3=src_s[e+3];
    float w0=w_s[e],  w1=w_s[e+1],  w2=w_s[e+2],  w3=w_s[e+3];
    const float4* p0 = reinterpret_cast<const float4*>(Ain) + (size_t)s0*768 + wv*192 + L;
    const float4* p1 = reinterpret_cast<const float4*>(Ain) + (size_t)s1*768 + wv*192 + L;
    const float4* p2 = reinterpret_cast<const float4*>(Ain) + (size_t)s2*768 + wv*192 + L;
    const float4* p3 = reinterpret_cast<const float4*>(Ain) + (size_t)s3*768 + wv*192 + L;
    float4 v0[3], v1[3], v2[3], v3[3];
    #pragma unroll
    for (int j=0;j<3;j++){ v0[j]=p0[j*64]; v1[j]=p1[j*64]; v2[j]=p2[j*64]; v3[j]=p3[j*64]; }
    #pragma unroll
    for (int j=0;j<3;j++){
      acc[j].x = fmaf(w0, v0[j].x, acc[j].x); acc[j].y = fmaf(w0, v0[j].y, acc[j].y);
      acc[j].z = fmaf(w0, v0[j].z, acc[j].z); acc[j].w = fmaf(w0, v0[j].w, acc[j].w);
      acc[j].x = fmaf(w1, v1[j].x, acc[j].x); acc[j].y = fmaf(w1, v1[j].y, acc[j].y);
      acc[j].z = fmaf(w1, v1[j].z, acc[j].z); acc[j].w = fmaf(w1, v1[j].w, acc[j].w);
      acc[j].x = fmaf(w2, v2[j].x, acc[j].x); acc[j].y = fmaf(w2, v2[j].y, acc[j].y);
      acc[j].z = fmaf(w2, v2[j].z, acc[j].z); acc[j].w = fmaf(w2, v2[j].w, acc[j].w);
      acc[j].x = fmaf(w3, v3[j].x, acc[j].x); acc[j].y = fmaf(w3, v3[j].y, acc[j].y);
      acc[j].z = fmaf(w3, v3[j].z, acc[j].z); acc[j].w = fmaf(w3, v3[j].w, acc[j].w);
    }
  }
  for (; e < end; ++e){
    int s0 = src_s[e]; float w0 = w_s[e];
    const float4* p0 = reinterpret_cast<const float4*>(Ain) + (size_t)s0*768 + wv*192 + L;
    #pragma unroll
    for (int j=0;j<3;j++){
      float4 v = p0[j*64];
      acc[j].x = fmaf(w0, v.x, acc[j].x); acc[j].y = fmaf(w0, v.y, acc[j].y);
      acc[j].z = fmaf(w0, v.z, acc[j].z); acc[j].w = fmaf(w0, v.w, acc[j].w);
    }
  }
  {
    int bt0 = wv*12 + (L>>4), c4 = (L&15)*4;
    #pragma unroll
    for (int j=0;j<3;j++)
      *reinterpret_cast<float4*>(Gs + (bt0 + j*4)*PAD_ + c4) = acc[j];
  }
  __syncthreads();
  int bt0 = wv*12 + (L>>4);
  int c4  = (L&15)*4;
  float4 bv = *reinterpret_cast<const float4*>(bc + c4);
  float4 out[3];
  #pragma unroll
  for (int j=0;j<3;j++) out[j] = bv;
  #pragma unroll 2
  for (int k4=0;k4<16;k4++){
    float4 wl[4], wr[4];
    #pragma unroll
    for (int i=0;i<4;i++){
      wl[i] = *reinterpret_cast<const float4*>(Wl + (k4*4+i)*H_ + c4);
      wr[i] = *reinterpret_cast<const float4*>(Wr + (k4*4+i)*H_ + c4);
    }
    #pragma unroll
    for (int j=0;j<3;j++){
      float4 g4 = *reinterpret_cast<const float4*>(Gs + (bt0 + j*4)*PAD_ + k4*4);
      float4 a4 = *reinterpret_cast<const float4*>(As + (bt0 + j*4)*PAD_ + k4*4);
      out[j].x = fmaf(g4.x, wl[0].x, out[j].x); out[j].y = fmaf(g4.x, wl[0].y, out[j].y);
      out[j].z = fmaf(g4.x, wl[0].z, out[j].z); out[j].w = fmaf(g4.x, wl[0].w, out[j].w);
      out[j].x = fmaf(g4.y, wl[1].x, out[j].x); out[j].y = fmaf(g4.y, wl[1].y, out[j].y);
      out[j].z = fmaf(g4.y, wl[1].z, out[j].z); out[j].w = fmaf(g4.y, wl[1].w, out[j].w);
      out[j].x = fmaf(g4.z, wl[2].x, out[j].x); out[j].y = fmaf(g4.z, wl[2].y, out[j].y);
      out[j].z = fmaf(g4.z, wl[2].z, out[j].z); out[j].w = fmaf(g4.z, wl[2].w, out[j].w);
      out[j].x = fmaf(g4.w, wl[3].x, out[j].x); out[j].y = fmaf(g4.w, wl[3].y, out[j].y);
      out[j].z = fmaf(g4.w, wl[3].z, out[j].z); out[j].w = fmaf(g4.w, wl[3].w, out[j].w);
      out[j].x = fmaf(a4.x, wr[0].x, out[j].x); out[j].y = fmaf(a4.x, wr[0].y, out[j].y);
      out[j].z = fmaf(a4.x, wr[0].z, out[j].z); out[j].w = fmaf(a4.x, wr[0].w, out[j].w);
      out[j].x = fmaf(a4.y, wr[1].x, out[j].x); out[j].y = fmaf(a4.y, wr[1].y, out[j].y);
      out[j].z = fmaf(a4.y, wr[1].z, out[j].z); out[j].w = fmaf(a4.y, wr[1].w, out[j].w);
      out[j].x = fmaf(a4.z, wr[2].x, out[j].x); out[j].y = fmaf(a4.z, wr[2].y, out[j].y);
      out[j].z = fmaf(a4.z, wr[2].z, out[j].z); out[j].w = fmaf(a4.z, wr[2].w, out[j].w);
      out[j].x = fmaf(a4.w, wr[3].x, out[j].x); out[j].y = fmaf(a4.w, wr[3].y, out[j].y);
      out[j].z = fmaf(a4.w, wr[3].z, out[j].z); out[j].w = fmaf(a4.w, wr[3].w, out[j].w);
    }
  }
  float4* Aout4 = reinterpret_cast<float4*>(Aout + (size_t)n*BT_*H_);
  #pragma unroll
  for (int j=0;j<3;j++){
    float4 o = out[j];
    o.x = fmaxf(o.x, 0.f); o.y = fmaxf(o.y, 0.f);
    o.z = fmaxf(o.z, 0.f); o.w = fmaxf(o.w, 0.f);
    Aout4[wv*192 + j*64 + L] = o;
  }
}

// ---------------------------------------------------------------------------
// GRU over T=12, [n][bt][h] layout. R12 structure (untested due to k_wstage
// transpose bug, now fixed):
//  - 8 waves/block (512 thr), 32 rows, grid 1250: finer makespan quantization
//    (critical CU 5 small blocks vs 3 big at 625-grid).
//  - Whh OFF the LDS pipe: k-major copy in global (k_wstage), 3 coalesced
//    dwordx4/k4/wave (49KB total, L2-resident, shared by all CUs).
//  - LDS reads/k4/wave: 10 -> 7 (3 Wih b128 + 4 h b128). LDS 56KB, 2 blk/CU.
//  - x from global uniform (R11 win). k4 unroll 4, t unroll 1 (R6 spill).
// Spill canaries: FETCH ~125MB, WRITE ~10MB. Revert bar: k_gru >= 450us.
// ---------------------------------------------------------------------------
__global__ __launch_bounds__(512) void k_gru(const float* __restrict__ A,
    const float* __restrict__ Wih, const float* __restrict__ Whh_k,
    const float* __restrict__ bih, const float* __restrict__ bhh,
    float* __restrict__ out){
  extern __shared__ float lds[];
  float* Wk = lds;                      // Wih k-major [3][16][64][4] = 12288 f (48KB)
  int tid = threadIdx.x;
  int wv = __builtin_amdgcn_readfirstlane(tid >> 6);
  int lane = tid & 63;
  float* hs = lds + 12288 + wv*256;     // [4][64] per-wave h slice (8KB total)
  // stage Wih k-major: dst = s*4096 + c4*256 + o*4   (3072 float4 / 512 thr)
  #pragma unroll
  for (int j=0;j<6;j++){
    int i = tid + j*512;                // float4 idx 0..3071
    int g = i >> 4, c4 = i & 15;
    int s = g >> 6, o = g & 63;
    float4 v = *reinterpret_cast<const float4*>(Wih + g*H_ + c4*4);
    *reinterpret_cast<float4*>(Wk + s*4096 + c4*256 + o*4) = v;
  }
  __syncthreads();
  float hreg[4];
  #pragma unroll
  for (int r=0;r<4;r++){ hreg[r] = 0.f; hs[r*64 + lane] = 0.f; }

  const float* wbi = Wk + lane*4;          // ih: + s*4096 + k4*256 (LDS)
  const float* wbh = Whh_k + lane*4;       // hh: + s*4096 + k4*256 (global/L2)

  int row0 = blockIdx.x*32 + wv*4;      // N_%4==0 -> wave rows share b
  int bb = row0 / N_;
  int nn0 = row0 - bb*N_;
  float bi[3], bh[3];
  #pragma unroll
  for (int s=0;s<3;s++){ bi[s] = bih[s*64 + lane]; bh[s] = bhh[s*64 + lane]; }
  // wave-uniform x row bases (t=0); advance by H_ per t
  const float* Ax0 = A + ((size_t)(nn0 + 0)*BT_ + bb*T_)*H_;
  const float* Ax1 = A + ((size_t)(nn0 + 1)*BT_ + bb*T_)*H_;
  const float* Ax2 = A + ((size_t)(nn0 + 2)*BT_ + bb*T_)*H_;
  const float* Ax3 = A + ((size_t)(nn0 + 3)*BT_ + bb*T_)*H_;

  #pragma unroll 1
  for (int t=0; t<T_; t++){
    const float* xrow[4] = { Ax0 + t*H_, Ax1 + t*H_, Ax2 + t*H_, Ax3 + t*H_ };

    float ai[3][4], ah[3][4];
    #pragma unroll
    for (int s=0;s<3;s++)
      #pragma unroll
      for (int r=0;r<4;r++){ ai[s][r] = bi[s]; ah[s][r] = bh[s]; }

    #pragma unroll 4
    for (int k4=0;k4<16;k4++){
      float4 wi[3], wh[3];
      #pragma unroll
      for (int s=0;s<3;s++){
        wi[s] = *reinterpret_cast<const float4*>(wbi + s*4096 + k4*256);  // LDS
        wh[s] = *reinterpret_cast<const float4*>(wbh + s*4096 + k4*256);  // global/L2
      }
      #pragma unroll
      for (int r=0;r<4;r++){
        float4 xw = *reinterpret_cast<const float4*>(xrow[r] + k4*4);  // uniform global
        float4 hw = *reinterpret_cast<const float4*>(hs + r*64 + k4*4);
        #pragma unroll
        for (int s=0;s<3;s++){
          ai[s][r] = fmaf(wi[s].x, xw.x, ai[s][r]);
          ai[s][r] = fmaf(wi[s].y, xw.y, ai[s][r]);
          ai[s][r] = fmaf(wi[s].z, xw.z, ai[s][r]);
          ai[s][r] = fmaf(wi[s].w, xw.w, ai[s][r]);
          ah[s][r] = fmaf(wh[s].x, hw.x, ah[s][r]);
          ah[s][r] = fmaf(wh[s].y, hw.y, ah[s][r]);
          ah[s][r] = fmaf(wh[s].z, hw.z, ah[s][r]);
          ah[s][r] = fmaf(wh[s].w, hw.w, ah[s][r]);
        }
      }
    }
    #pragma unroll
    for (int r=0;r<4;r++){
      float rr = sigmoidf_(ai[0][r] + ah[0][r]);
      float zz = sigmoidf_(ai[1][r] + ah[1][r]);
      float ng = tanhf_(ai[2][r] + rr*ah[2][r]);
      float hn = (1.f - zz)*ng + zz*hreg[r];
      hreg[r] = hn;
      hs[r*64 + lane] = hn;
    }
  }
  #pragma unroll
  for (int r=0;r<4;r++)
    out[(size_t)(row0 + r)*H_ + lane] = hreg[r];
}

// ---------------------------------------------------------------------------
extern "C" void kernel_launch(void* const* d_in, const int* in_sizes, int n_in,
                              void* d_out, int out_size, void* d_ws, size_t ws_size,
                              hipStream_t stream){
  const float* x     = (const float*)d_in[0];
  const int*   ei    = (const int*)d_in[1];
  const float* ew    = (const float*)d_in[2];
  const float* Wpre  = (const float*)d_in[3];
  const float* bpre  = (const float*)d_in[4];
  const float* Wlin  = (const float*)d_in[5];
  const float* Wroot = (const float*)d_in[6];
  const float* bconv = (const float*)d_in[7];
  const float* Wih   = (const float*)d_in[8];
  const float* Whh   = (const float*)d_in[9];
  const float* bih   = (const float*)d_in[10];
  const float* bhh   = (const float*)d_in[11];
  float* out = (float*)d_out;

  float* ws   = (float*)d_ws;
  float* A0   = ws;                       // 30,720,000 f  [n][bt][h]
  float* A1   = A0 + (size_t)ROWS_*H_;    // 30,720,000 f
  float* wdeg = A1 + (size_t)ROWS_*H_;    // N
  float* dinv = wdeg + N_;                // N
  float* w_s  = dinv + N_;                // E
  int*   cnt   = (int*)(w_s + E_);        // N
  int*   fillc = cnt + N_;                // N
  int*   rs    = fillc + N_;              // N+1
  int*   src_s = rs + (N_+1);             // E
  float* Whh_k = (float*)(src_s + E_);    // 12288 f (k-major Whh copy)
  // total ~247 MB (known-safe)

  hipMemsetAsync(wdeg, 0, N_*sizeof(float), stream);
  hipMemsetAsync(cnt,  0, 2*N_*sizeof(int), stream);   // cnt + fillc contiguous

  k_pre<<<ROWS_/256, 256, 0, stream>>>(x, Wpre, bpre, A0);
  k_deg<<<E_/256, 256, 0, stream>>>(ei, ew, wdeg, cnt);
  k_scan<<<1, 1024, 0, stream>>>(cnt, rs);
  k_dinv<<<(N_+255)/256, 256, 0, stream>>>(wdeg, dinv);
  k_fill<<<E_/256, 256, 0, stream>>>(ei, ew, dinv, rs, fillc, src_s, w_s);
  k_wstage<<<48, 256, 0, stream>>>(Whh, Whh_k);

  k_agg<<<N_, 256, 0, stream>>>(A0, A1, Wlin,         Wroot,         bconv,
                                rs, src_s, w_s);
  k_agg<<<N_, 256, 0, stream>>>(A1, A0, Wlin + H_*H_, Wroot + H_*H_, bconv + H_,
                                rs, src_s, w_s);

  hipFuncSetAttribute((const void*)k_gru,
      hipFuncAttributeMaxDynamicSharedMemorySize, 57344);
  k_gru<<<GRU_ROWS_/32, 512, 57344, stream>>>(A0, Wih, Whh_k, bih, bhh, out);
}